// Round 17
// baseline (542.393 us; speedup 1.0000x reference)
//
#include <hip/hip_runtime.h>
#include <hip/hip_bf16.h>
#include <math.h>

using bf16 = __hip_bfloat16;
typedef __attribute__((ext_vector_type(8))) short bf16x8;
typedef __attribute__((ext_vector_type(4))) float f32x4;

__device__ __forceinline__ float b2f(unsigned short u) {
  return __uint_as_float(((unsigned)u) << 16);
}
__device__ __forceinline__ unsigned short f2b(float f) {
  bf16 h = __float2bfloat16(f);  // RNE
  return *reinterpret_cast<unsigned short*>(&h);
}
__device__ __forceinline__ ushort4 f2b4(float4 v) {
  return make_ushort4(f2b(v.x), f2b(v.y), f2b(v.z), f2b(v.w));
}

// ---------------------------------------------------------------------------
// MFMA bf16 GEMM: xib = bf16(x @ W_aff^T + b_aff) into xcat right half.
// Reads x (f32) directly and write-throughs xb (bf16) into xcat left half
// during staging — deletes the separate cvt pass (51MB read + 26MB write).
// ---------------------------------------------------------------------------
__global__ __launch_bounds__(256) void mgemm_k(
    const float* __restrict__ x, unsigned short* __restrict__ xcat,
    const float* __restrict__ W, const float* __restrict__ bias, int N) {
  constexpr int LDA = 72;
  __shared__ unsigned short As[128 * LDA];
  __shared__ unsigned short Ws[128 * LDA];

  const int tid = threadIdx.x;
  const int lane = tid & 63;
  const int wave = tid >> 6;
  const int row0 = blockIdx.x * 128;
  const int rowhalf = (wave & 1) * 64;
  const int colhalf = (wave >> 1) * 64;
  const int l15 = lane & 15;
  const int quad = lane >> 4;

  f32x4 acc[4][4] = {};

  for (int kc = 0; kc < 128; kc += 64) {
#pragma unroll
    for (int i = 0; i < 4; i++) {
      int idx = tid + i * 256;
      int r = idx >> 3;
      int k8 = (idx & 7) * 8;
      int row = row0 + r;
      ushort4 u0 = make_ushort4(0, 0, 0, 0), u1 = u0;
      if (row < N) {
        const float* s = x + (size_t)row * 128 + kc + k8;
        u0 = f2b4(*(const float4*)s);
        u1 = f2b4(*(const float4*)(s + 4));
        // write-through xb into xcat left half
        *(ushort4*)&xcat[(size_t)row * 256 + kc + k8] = u0;
        *(ushort4*)&xcat[(size_t)row * 256 + kc + k8 + 4] = u1;
      }
      *(ushort4*)&As[r * LDA + k8] = u0;
      *(ushort4*)&As[r * LDA + k8 + 4] = u1;
    }
#pragma unroll
    for (int i = 0; i < 8; i++) {
      int idx = tid + i * 256;
      int r = idx >> 4;
      int k4 = idx & 15;
      float4 v = *(const float4*)(W + (size_t)r * 128 + kc + k4 * 4);
      *(ushort4*)&Ws[r * LDA + k4 * 4] = f2b4(v);
    }
    __syncthreads();
#pragma unroll
    for (int ks = 0; ks < 2; ks++) {
      const int ko = ks * 32 + quad * 8;
      bf16x8 af[4], wf[4];
#pragma unroll
      for (int ri = 0; ri < 4; ri++)
        af[ri] = *(const bf16x8*)&As[(rowhalf + ri * 16 + l15) * LDA + ko];
#pragma unroll
      for (int ci = 0; ci < 4; ci++)
        wf[ci] = *(const bf16x8*)&Ws[(colhalf + ci * 16 + l15) * LDA + ko];
#pragma unroll
      for (int ri = 0; ri < 4; ri++)
#pragma unroll
        for (int ci = 0; ci < 4; ci++)
          acc[ri][ci] = __builtin_amdgcn_mfma_f32_16x16x32_bf16(
              af[ri], wf[ci], acc[ri][ci], 0, 0, 0);
    }
    __syncthreads();
  }
#pragma unroll
  for (int ci = 0; ci < 4; ci++) {
    const int col = colhalf + ci * 16 + l15;
    const float bv = bias[col];
#pragma unroll
    for (int ri = 0; ri < 4; ri++) {
      const int rbase = row0 + rowhalf + ri * 16 + quad * 4;
#pragma unroll
      for (int r = 0; r < 4; r++) {
        int row = rbase + r;
        if (row >= N) continue;
        xcat[(size_t)row * 256 + 128 + col] = f2b(acc[ri][ci][r] + bv);
      }
    }
  }
}

// ---------------------------------------------------------------------------
// FUSED GRU + backbone, 64-row tiles, 8 waves (512 thr), 2 blocks/CU.
// Writes pre-BN output as bf16 into hout (aliases aggs). setprio(1) around
// MFMA clusters (T5). Stats from f32 regs.
// ---------------------------------------------------------------------------
__global__ __launch_bounds__(512, 4) void grubb_k(
    const unsigned short* __restrict__ aggm,
    const unsigned short* __restrict__ xcat,
    const unsigned short* __restrict__ aggs,
    const unsigned short* __restrict__ Wbig,
    const float* __restrict__ bias_big,
    const unsigned short* __restrict__ Wmb, const float* __restrict__ bm,
    const unsigned short* __restrict__ W1b, const float* __restrict__ b1,
    const unsigned short* __restrict__ W2b, const float* __restrict__ b2,
    const float* __restrict__ epsp, unsigned short* __restrict__ hout,
    float* __restrict__ pstats, int N) {
  constexpr int LDA = 264;  // 256 + 8 pad (ushorts)
  constexpr int LDH = 136;  // 128 + 8 pad
  __shared__ unsigned short As[64 * LDA];    // [aggm | xb]; later Hd alias
  __shared__ unsigned short Acat[64 * LDA];  // [aggs | rnn]; later Hp alias
  __shared__ float sbn[128], qbn[128];
  unsigned short* Hd = As;    // As dead after Hp-write phase
  unsigned short* Hp = Acat;  // Acat dead after merge MFMA

  const int tid = threadIdx.x;
  const int lane = tid & 63;
  const int wave = tid >> 6;  // 0..7
  const int l15 = lane & 15;
  const int quad = lane >> 4;
  const int row0 = blockIdx.x * 64;
  if (tid < 128) {
    sbn[tid] = 0.f;
    qbn[tid] = 0.f;
  }
  const float ep = epsp[0];
  const int f = wave * 16 + l15;  // this lane's feature / output col

  {  // phase 0: stage As (32 ushorts/thread) + Acat left (16 ushorts/thread)
    int r = tid >> 3;  // 0..63
    int q = tid & 7;
    int row = row0 + r;
    int k32 = q * 32;
    uint4 u[4] = {};
    uint4 v[2] = {};
    if (row < N) {
      const unsigned short* s = (k32 < 128)
                                    ? aggm + (size_t)row * 128 + k32
                                    : xcat + (size_t)row * 256 + (k32 - 128);
#pragma unroll
      for (int i = 0; i < 4; i++) u[i] = *(const uint4*)(s + i * 8);
      const unsigned short* s2 = aggs + (size_t)row * 128 + q * 16;
      v[0] = *(const uint4*)s2;
      v[1] = *(const uint4*)(s2 + 8);
    }
#pragma unroll
    for (int i = 0; i < 4; i++) *(uint4*)&As[r * LDA + k32 + i * 8] = u[i];
    *(uint4*)&Acat[r * LDA + q * 16] = v[0];
    *(uint4*)&Acat[r * LDA + q * 16 + 8] = v[1];
  }
  __syncthreads();  // B1

  {  // phase 1: GRU MFMA, 64 rows, zero-skip on gate2/gate3 half-K
    const unsigned short* wp[4];
#pragma unroll
    for (int g = 0; g < 4; g++)
      wp[g] = Wbig +
              (size_t)((wave >> 1) * 128 + (g + 4 * (wave & 1)) * 16 + l15) *
                  256 +
              quad * 8;
    f32x4 acc[4][4] = {};
    __builtin_amdgcn_s_setprio(1);
#pragma unroll
    for (int ks = 0; ks < 8; ks++) {
      const int ko = ks * 32 + quad * 8;
      bf16x8 af[4];
#pragma unroll
      for (int ri = 0; ri < 4; ri++)
        af[ri] = *(const bf16x8*)&As[(ri * 16 + l15) * LDA + ko];
#pragma unroll
      for (int g = 0; g < 4; g++) {
        if (g == 2 && ks >= 4) continue;  // W_ih n-gate: zero for k>=128
        if (g == 3 && ks < 4) continue;   // W_hh n-gate: zero for k<128
        bf16x8 wf = *(const bf16x8*)(wp[g] + ks * 32);
#pragma unroll
        for (int ri = 0; ri < 4; ri++)
          acc[ri][g] = __builtin_amdgcn_mfma_f32_16x16x32_bf16(
              af[ri], wf, acc[ri][g], 0, 0, 0);
      }
    }
    __builtin_amdgcn_s_setprio(0);
    // register GRU: acc[ri][g][r], row rl = ri*16 + quad*4 + r
    const float br = bias_big[f];
    const float bz = bias_big[128 + f];
    const float bi = bias_big[256 + f];
    const float bh = bias_big[384 + f];
#pragma unroll
    for (int ri = 0; ri < 4; ri++) {
#pragma unroll
      for (int r = 0; r < 4; r++) {
        int rl = ri * 16 + quad * 4 + r;
        float rg = 1.f / (1.f + __expf(-(acc[ri][0][r] + br)));
        float zg = 1.f / (1.f + __expf(-(acc[ri][1][r] + bz)));
        float a = acc[ri][2][r] + bi + rg * (acc[ri][3][r] + bh);
        float t = 1.f - 2.f / (__expf(2.f * fabsf(a)) + 1.f);
        float nc = copysignf(t, a);
        float xv = b2f(As[rl * LDA + 128 + f]);  // xb staged in LDS
        Acat[rl * LDA + 128 + f] = f2b((1.f - zg) * nc + zg * xv);
      }
    }
  }
  __syncthreads();  // B2

  f32x4 accm[4] = {};
  {  // phase 2: merge MFMA (K=256 over Acat); wave w -> col f
    const unsigned short* wptr = Wmb + (size_t)f * 256 + quad * 8;
    __builtin_amdgcn_s_setprio(1);
#pragma unroll
    for (int ks = 0; ks < 8; ks++) {
      const int ko = ks * 32 + quad * 8;
      bf16x8 w0 = *(const bf16x8*)(wptr + ks * 32);
#pragma unroll
      for (int ri = 0; ri < 4; ri++) {
        bf16x8 af = *(const bf16x8*)&Acat[(ri * 16 + l15) * LDA + ko];
        accm[ri] = __builtin_amdgcn_mfma_f32_16x16x32_bf16(af, w0, accm[ri],
                                                           0, 0, 0);
      }
    }
    __builtin_amdgcn_s_setprio(0);
  }
  __syncthreads();  // B3: all Acat readers done before Hp overwrite
  {  // merge epilogue: + bm + eps*xb -> Hp (aliases Acat)
    float bv = bm[f];
#pragma unroll
    for (int ri = 0; ri < 4; ri++) {
#pragma unroll
      for (int r = 0; r < 4; r++) {
        int rl = ri * 16 + quad * 4 + r;
        float v = accm[ri][r] + bv + ep * b2f(As[rl * LDA + 128 + f]);
        Hp[rl * LDH + f] = f2b(v);
      }
    }
  }
  __syncthreads();  // B4

  f32x4 acc3[4] = {};
#pragma unroll
  for (int hh = 0; hh < 2; hh++) {
    // W1 half hh: Hd = relu(Hp @ W1[hh*128..+128]^T + b1); wave w -> col f
    f32x4 acc2[4] = {};
    {
      const unsigned short* wptr =
          W1b + (size_t)(hh * 128 + f) * 128 + quad * 8;
      __builtin_amdgcn_s_setprio(1);
#pragma unroll
      for (int ks = 0; ks < 4; ks++) {
        const int ko = ks * 32 + quad * 8;
        bf16x8 w0 = *(const bf16x8*)(wptr + ks * 32);
#pragma unroll
        for (int ri = 0; ri < 4; ri++) {
          bf16x8 af = *(const bf16x8*)&Hp[(ri * 16 + l15) * LDH + ko];
          acc2[ri] = __builtin_amdgcn_mfma_f32_16x16x32_bf16(af, w0, acc2[ri],
                                                             0, 0, 0);
        }
      }
      __builtin_amdgcn_s_setprio(0);
    }
    __syncthreads();  // prior Hd readers (W2 of hh-1) done before overwrite
    {
      float bv = b1[hh * 128 + f];
#pragma unroll
      for (int ri = 0; ri < 4; ri++) {
#pragma unroll
        for (int r = 0; r < 4; r++) {
          int rl = ri * 16 + quad * 4 + r;
          Hd[rl * LDH + f] = f2b(fmaxf(acc2[ri][r] + bv, 0.f));
        }
      }
    }
    __syncthreads();
    // W2 half hh: acc3 += Hd @ W2[:, hh*128..+128]^T
    {
      const unsigned short* wptr =
          W2b + (size_t)f * 256 + hh * 128 + quad * 8;
      __builtin_amdgcn_s_setprio(1);
#pragma unroll
      for (int ks = 0; ks < 4; ks++) {
        const int ko = ks * 32 + quad * 8;
        bf16x8 w0 = *(const bf16x8*)(wptr + ks * 32);
#pragma unroll
        for (int ri = 0; ri < 4; ri++) {
          bf16x8 af = *(const bf16x8*)&Hd[(ri * 16 + l15) * LDH + ko];
          acc3[ri] = __builtin_amdgcn_mfma_f32_16x16x32_bf16(af, w0, acc3[ri],
                                                             0, 0, 0);
        }
      }
      __builtin_amdgcn_s_setprio(0);
    }
  }
  // epilogue: relu + hout (bf16) + BN partials (f32, from regs)
  {
    float bv = b2[f];
    float s = 0.f, q = 0.f;
#pragma unroll
    for (int ri = 0; ri < 4; ri++) {
#pragma unroll
      for (int r = 0; r < 4; r++) {
        int rl = ri * 16 + quad * 4 + r;
        int row = row0 + rl;
        if (row >= N) continue;
        float v = fmaxf(acc3[ri][r] + bv, 0.f);
        hout[(size_t)row * 128 + f] = f2b(v);
        s += v;
        q += v * v;
      }
    }
    atomicAdd(&sbn[f], s);
    atomicAdd(&qbn[f], q);
  }
  __syncthreads();
  if (tid < 128) {
    float* p = pstats + (size_t)blockIdx.x * 256;
    p[tid] = sbn[tid];
    p[128 + tid] = qbn[tid];
  }
}

// ---------------------------------------------------------------------------
// bnred: reduce per-block partials -> stats (few, well-spread atomics)
// ---------------------------------------------------------------------------
__global__ __launch_bounds__(256) void bnred_k(const float* __restrict__ pstats,
                                               float* __restrict__ stats,
                                               int nb) {
  int t = threadIdx.x;
  float s = 0.f;
  for (int b = blockIdx.x; b < nb; b += gridDim.x)
    s += pstats[(size_t)b * 256 + t];
  atomicAdd(&stats[t], s);
}

// ---------------------------------------------------------------------------
// prep: permuted Wbig, Wmb/W1b/W2b bf16 copies, bias_big, zero stats + deg.
// ---------------------------------------------------------------------------
__global__ __launch_bounds__(256) void prep_k(
    const float* __restrict__ W_ih, const float* __restrict__ b_ih,
    const float* __restrict__ W_hh, const float* __restrict__ b_hh,
    const float* __restrict__ Wm, const float* __restrict__ W1,
    const float* __restrict__ W2, unsigned short* __restrict__ Wbig,
    unsigned short* __restrict__ Wmb, unsigned short* __restrict__ W1b,
    unsigned short* __restrict__ W2b, float* __restrict__ bias_big,
    float* __restrict__ stats, int* __restrict__ deg, int N) {
  int idx = blockIdx.x * 256 + threadIdx.x;
  if (idx < N) deg[idx] = 0;
  if (idx < 32768) {  // permuted Wbig: col c -> (gate g, feature f)
    int mp = idx >> 6;
    int k4 = (idx & 63) * 4;
    int w = mp >> 7, ci = (mp >> 4) & 7, l15 = mp & 15;
    int g = ci & 3, fi = ci >> 2;
    int f = w * 32 + fi * 16 + l15;
    const float* src = nullptr;
    int koff = 0;
    if (g <= 1) {
      int m = g * 128 + f;
      if (k4 < 128) { src = W_ih + (size_t)m * 128; koff = k4; }
      else          { src = W_hh + (size_t)m * 128; koff = k4 - 128; }
    } else if (g == 2) {
      if (k4 < 128) { src = W_ih + (size_t)(256 + f) * 128; koff = k4; }
    } else {
      if (k4 >= 128) { src = W_hh + (size_t)(256 + f) * 128; koff = k4 - 128; }
    }
    ushort4 o = make_ushort4(0, 0, 0, 0);
    if (src) o = f2b4(*(const float4*)(src + koff));
    *(ushort4*)&Wbig[(size_t)mp * 256 + k4] = o;
  }
  if (idx < 8192) {
    int m = idx >> 6;
    int k4 = (idx & 63) * 4;
    *(ushort4*)&Wmb[(size_t)m * 256 + k4] =
        f2b4(*(const float4*)(Wm + (size_t)m * 256 + k4));
    *(ushort4*)&W2b[(size_t)m * 256 + k4] =
        f2b4(*(const float4*)(W2 + (size_t)m * 256 + k4));
    int m2 = idx >> 5;
    int k42 = (idx & 31) * 4;
    *(ushort4*)&W1b[(size_t)m2 * 128 + k42] =
        f2b4(*(const float4*)(W1 + (size_t)m2 * 128 + k42));
  }
  if (blockIdx.x == 0) {
    int t = threadIdx.x;
    stats[t] = 0.f;
#pragma unroll
    for (int h = 0; h < 2; h++) {
      int mm = t + h * 256;
      float b;
      if (mm < 256) b = b_ih[mm] + b_hh[mm];
      else if (mm < 384) b = b_ih[mm];
      else b = b_hh[mm - 128];
      bias_big[mm] = b;
    }
  }
}

// ---------------------------------------------------------------------------
// hist: per-node in-degree histogram
// ---------------------------------------------------------------------------
__global__ __launch_bounds__(256) void hist_k(const int* __restrict__ edges,
                                              int* __restrict__ deg, int E) {
  int e = blockIdx.x * 256 + threadIdx.x;
  if (e < E) atomicAdd(&deg[edges[(size_t)E + e]], 1);
}

// ---------------------------------------------------------------------------
// CSR scan
// ---------------------------------------------------------------------------
__global__ __launch_bounds__(256) void scan1_k(const int* __restrict__ deg,
                                               int* __restrict__ off,
                                               int* __restrict__ bsums, int N) {
  __shared__ int s[256];
  int t = threadIdx.x;
  int i = blockIdx.x * 256 + t;
  int v = (i < N) ? deg[i] : 0;
  s[t] = v;
  __syncthreads();
#pragma unroll
  for (int d = 1; d < 256; d <<= 1) {
    int u = (t >= d) ? s[t - d] : 0;
    __syncthreads();
    s[t] += u;
    __syncthreads();
  }
  if (i < N) off[i] = s[t] - v;
  if (t == 255) bsums[blockIdx.x] = s[255];
}

__global__ __launch_bounds__(512) void scan2_k(int* __restrict__ bsums,
                                               int nb) {
  __shared__ int s[512];
  int t = threadIdx.x;
  int v = (t < nb) ? bsums[t] : 0;
  s[t] = v;
  __syncthreads();
#pragma unroll
  for (int d = 1; d < 512; d <<= 1) {
    int u = (t >= d) ? s[t - d] : 0;
    __syncthreads();
    s[t] += u;
    __syncthreads();
  }
  if (t < nb) bsums[t] = s[t] - v;
}

// scan3: finalize off[] and also emit per-bin (512 nodes) offsets + cursors.
__global__ __launch_bounds__(256) void scan3_k(int* __restrict__ off,
                                               const int* __restrict__ bsums,
                                               int* __restrict__ binoff,
                                               int* __restrict__ bincur,
                                               int N, int E, int NB) {
  int i = blockIdx.x * 256 + threadIdx.x;
  if (i < N) {
    int o = off[i] + bsums[blockIdx.x];
    off[i] = o;
    if ((i & 511) == 0) {
      binoff[i >> 9] = o;
      bincur[i >> 9] = o;
    }
  }
  if (i == 0) {
    off[N] = E;
    binoff[NB] = E;
  }
}

// ---------------------------------------------------------------------------
// edgepart: bin edges by dst>>9 into part[] (packed (src<<9)|(dst&511)).
// ---------------------------------------------------------------------------
__global__ __launch_bounds__(256) void edgepart_k(const int* __restrict__ edges,
                                                  int* __restrict__ bincur,
                                                  int* __restrict__ part,
                                                  int E, int NB) {
  __shared__ int cnt[256];
  const int tid = threadIdx.x;
  if (tid < NB) cnt[tid] = 0;
  __syncthreads();
  int sv[16], dv[16];
  const int e0 = blockIdx.x * 4096;
#pragma unroll
  for (int i = 0; i < 16; i++) {
    int e = e0 + i * 256 + tid;
    int s = 0, d = -1;
    if (e < E) {
      s = edges[e];
      d = edges[(size_t)E + e];
    }
    sv[i] = s;
    dv[i] = d;
    if (d >= 0) atomicAdd(&cnt[d >> 9], 1);
  }
  __syncthreads();
  if (tid < NB) {
    int c = cnt[tid];
    int base = c ? atomicAdd(&bincur[tid], c) : 0;
    cnt[tid] = base;  // becomes running cursor
  }
  __syncthreads();
#pragma unroll
  for (int i = 0; i < 16; i++) {
    int d = dv[i];
    if (d < 0) continue;
    int p = atomicAdd(&cnt[d >> 9], 1);
    part[p] = (sv[i] << 9) | (d & 511);
  }
}

// ---------------------------------------------------------------------------
// fill2: one block per bin; node cursors in LDS; writes confined to the
// bin's contiguous bucket window.
// ---------------------------------------------------------------------------
__global__ __launch_bounds__(1024) void fill2_k(const int* __restrict__ off,
                                                const int* __restrict__ binoff,
                                                const int* __restrict__ part,
                                                int* __restrict__ bucket,
                                                int N) {
  __shared__ int scur[512];
  const int b = blockIdx.x;
  const int n0 = b << 9;
  const int tid = threadIdx.x;
  if (tid < 512) {
    int node = n0 + tid;
    scur[tid] = (node < N) ? off[node] : 0;
  }
  __syncthreads();
  const int j0 = binoff[b];
  const int j1 = binoff[b + 1];
  for (int j = j0 + tid; j < j1; j += 1024) {
    int p = part[j];
    int pos = atomicAdd(&scur[p & 511], 1);
    bucket[pos] = p >> 9;
  }
}

// ---------------------------------------------------------------------------
// gather-reduce: one wave/node, EIGHTH-wave edge split — 8 edges in flight
// (2x r16's quarter-wave), 8 lanes/edge, 16 features/lane via 2x 16B uint4
// loads. Three-level shfl_xor(8/16/32) combine. Writes aggs + aggm.
// ---------------------------------------------------------------------------
__global__ __launch_bounds__(256) void gather_k(
    const int* __restrict__ off, const int* __restrict__ bucket,
    const unsigned short* __restrict__ xcat, unsigned short* __restrict__ aggm,
    unsigned short* __restrict__ aggs, int N) {
  int node = blockIdx.x * 4 + (threadIdx.x >> 6);
  if (node >= N) return;
  const int lane = threadIdx.x & 63;
  const int oct = lane >> 3;        // eighth index 0..7
  const int f16 = (lane & 7) * 16;  // 16 features per lane
  const int j0 = off[node], jend = off[node + 1];
  float s[16], m[16];
#pragma unroll
  for (int i = 0; i < 16; i++) {
    s[i] = 0.f;
    m[i] = -INFINITY;
  }
  int jj = j0 + oct;
  int p0 = (jj < jend) ? bucket[jj] : 0;
  int p1 = (jj + 8 < jend) ? bucket[jj + 8] : 0;
  for (; jj < jend; jj += 8) {
    int src = p0;
    p0 = p1;
    p1 = (jj + 16 < jend) ? bucket[jj + 16] : 0;
    uint4 a0 = *(const uint4*)(xcat + (size_t)src * 256 + f16);
    uint4 a1 = *(const uint4*)(xcat + (size_t)src * 256 + f16 + 8);
    uint4 b0 = *(const uint4*)(xcat + (size_t)src * 256 + 128 + f16);
    uint4 b1 = *(const uint4*)(xcat + (size_t)src * 256 + 128 + f16 + 8);
    const unsigned short* ap0 = (const unsigned short*)&a0;
    const unsigned short* ap1 = (const unsigned short*)&a1;
    const unsigned short* bp0 = (const unsigned short*)&b0;
    const unsigned short* bp1 = (const unsigned short*)&b1;
#pragma unroll
    for (int i = 0; i < 8; i++) {
      s[i] += b2f(ap0[i]);
      s[8 + i] += b2f(ap1[i]);
      m[i] = fmaxf(m[i], b2f(bp0[i]));
      m[8 + i] = fmaxf(m[8 + i], b2f(bp1[i]));
    }
  }
  // combine the eight eighth-waves
#pragma unroll
  for (int i = 0; i < 16; i++) {
    s[i] += __shfl_xor(s[i], 8);
    s[i] += __shfl_xor(s[i], 16);
    s[i] += __shfl_xor(s[i], 32);
    m[i] = fmaxf(m[i], __shfl_xor(m[i], 8));
    m[i] = fmaxf(m[i], __shfl_xor(m[i], 16));
    m[i] = fmaxf(m[i], __shfl_xor(m[i], 32));
  }
  if (oct == 0) {
    bool nz = jend > j0;
    unsigned short mv[16], sv[16];
#pragma unroll
    for (int i = 0; i < 16; i++) {
      mv[i] = nz ? f2b(m[i]) : (unsigned short)0;
      sv[i] = f2b(s[i]);
    }
    *(uint4*)&aggm[(size_t)node * 128 + f16] = *(const uint4*)mv;
    *(uint4*)&aggm[(size_t)node * 128 + f16 + 8] = *(const uint4*)(mv + 8);
    *(uint4*)&aggs[(size_t)node * 128 + f16] = *(const uint4*)sv;
    *(uint4*)&aggs[(size_t)node * 128 + f16 + 8] = *(const uint4*)(sv + 8);
  }
}

// ---------------------------------------------------------------------------
// BatchNorm apply: read pre-BN bf16 hout, write final f32 out.
// ---------------------------------------------------------------------------
__global__ __launch_bounds__(256) void bn_apply_k(
    float* __restrict__ out, const unsigned short* __restrict__ hout,
    const float* __restrict__ stats, const float* __restrict__ gamma,
    const float* __restrict__ beta, float invn, int nd4) {
  int g = blockIdx.x * 256 + threadIdx.x;
  if (g >= nd4) return;
  int d = (g & 31) * 4;
  ushort4 hv = ((const ushort4*)hout)[g];
  float o[4] = {b2f(hv.x), b2f(hv.y), b2f(hv.z), b2f(hv.w)};
#pragma unroll
  for (int i = 0; i < 4; i++) {
    float mean = stats[d + i] * invn;
    float var = fmaxf(stats[128 + d + i] * invn - mean * mean, 0.f);
    float sc = gamma[d + i] * rsqrtf(var + 1e-5f);
    o[i] = (o[i] - mean) * sc + beta[d + i];
  }
  ((float4*)out)[g] = make_float4(o[0], o[1], o[2], o[3]);
}

// ---------------------------------------------------------------------------
extern "C" void kernel_launch(void* const* d_in, const int* in_sizes, int n_in,
                              void* d_out, int out_size, void* d_ws,
                              size_t ws_size, hipStream_t stream) {
  (void)n_in;
  (void)out_size;
  (void)ws_size;
  const float* x = (const float*)d_in[0];
  const int* edges = (const int*)d_in[1];
  const float* W_aff = (const float*)d_in[2];
  const float* b_aff = (const float*)d_in[3];
  const float* W_ih = (const float*)d_in[4];
  const float* b_ih = (const float*)d_in[5];
  const float* W_hh = (const float*)d_in[6];
  const float* b_hh = (const float*)d_in[7];
  const float* W_merge = (const float*)d_in[8];
  const float* b_merge = (const float*)d_in[9];
  const float* epsp = (const float*)d_in[10];
  const float* W1 = (const float*)d_in[11];
  const float* b1 = (const float*)d_in[12];
  const float* W2 = (const float*)d_in[13];
  const float* b2 = (const float*)d_in[14];
  const float* gamma = (const float*)d_in[15];
  const float* beta = (const float*)d_in[16];

  const int N = in_sizes[0] / 128;
  const int E = in_sizes[1] / 2;
  const size_t nd = (size_t)N * 128;
  const int NB = (N + 511) >> 9;   // 512-node bins
  const int gblk = (N + 63) / 64;  // grubb grid (64-row tiles)

  // ---- workspace ----
  char* base = (char*)d_ws;
  unsigned short* xcat = (unsigned short*)base;               // [xb|xib] Nx256
  unsigned short* aggs = (unsigned short*)(base + (size_t)N * 512);  // Nx128 sum
  unsigned short* aggm = (unsigned short*)(base + (size_t)N * 1024); // Nx128 max
  unsigned short* Wbig = (unsigned short*)(base + (size_t)N * 1280);
  unsigned short* Wmb = Wbig + 512 * 256;
  unsigned short* W1b = Wmb + 128 * 256;
  unsigned short* W2b = W1b + 256 * 128;
  float* bias_big = (float*)(W2b + 128 * 256);
  float* stats = bias_big + 512;
  int* deg = (int*)(stats + 512);
  int* off = deg + N;
  int* binoff = off + N + 1;
  int* bincur = binoff + NB + 1;
  int* bucket = bincur + NB;
  int* bsums = bucket + E;
  float* pstats = (float*)(bsums + ((N + 255) / 256));  // gblk x 256 partials
  float* out = (float*)d_out;
  // hout (pre-BN bf16) aliases aggs: block b's hout rows are exactly the
  // aggs rows only block b reads (phase 0), disjoint across blocks.
  unsigned short* hout = aggs;
  // part[] (E ints) lives in d_out: dead before bn_apply writes out.
  int* part = (int*)d_out;

  const int ny = (N + 127) / 128;
  const int nblk = (N + 255) / 256;
  const int eblk = (E + 255) / 256;
  const int pgrid = nblk > 128 ? nblk : 128;
  dim3 blk(256);

  prep_k<<<pgrid, blk, 0, stream>>>(W_ih, b_ih, W_hh, b_hh, W_merge, W1, W2,
                                    Wbig, Wmb, W1b, W2b, bias_big, stats, deg,
                                    N);
  hist_k<<<eblk, blk, 0, stream>>>(edges, deg, E);
  scan1_k<<<nblk, blk, 0, stream>>>(deg, off, bsums, N);
  scan2_k<<<1, 512, 0, stream>>>(bsums, nblk);
  scan3_k<<<nblk, blk, 0, stream>>>(off, bsums, binoff, bincur, N, E, NB);
  edgepart_k<<<(E + 4095) / 4096, blk, 0, stream>>>(edges, bincur, part, E, NB);
  fill2_k<<<NB, dim3(1024), 0, stream>>>(off, binoff, part, bucket, N);

  // xb (write-through) + xib = bf16(x @ W_aff^T + b_aff) into xcat
  mgemm_k<<<ny, blk, 0, stream>>>(x, xcat, W_aff, b_aff, N);
  gather_k<<<(N + 3) / 4, blk, 0, stream>>>(off, bucket, xcat, aggm, aggs, N);
  grubb_k<<<gblk, dim3(512), 0, stream>>>(aggm, xcat, aggs, Wbig, bias_big,
                                          Wmb, b_merge, W1b, b1, W2b, b2,
                                          epsp, hout, pstats, N);
  bnred_k<<<64, blk, 0, stream>>>(pstats, stats, gblk);
  bn_apply_k<<<(int)((nd / 4 + 255) / 256), blk, 0, stream>>>(
      out, hout, stats, gamma, beta, 1.f / (float)N, (int)(nd / 4));
}

// Round 18
// 536.301 us; speedup vs baseline: 1.0114x; 1.0114x over previous
//
#include <hip/hip_runtime.h>
#include <hip/hip_bf16.h>
#include <math.h>

using bf16 = __hip_bfloat16;
typedef __attribute__((ext_vector_type(8))) short bf16x8;
typedef __attribute__((ext_vector_type(4))) float f32x4;

__device__ __forceinline__ float b2f(unsigned short u) {
  return __uint_as_float(((unsigned)u) << 16);
}
__device__ __forceinline__ unsigned short f2b(float f) {
  bf16 h = __float2bfloat16(f);  // RNE
  return *reinterpret_cast<unsigned short*>(&h);
}
__device__ __forceinline__ ushort4 f2b4(float4 v) {
  return make_ushort4(f2b(v.x), f2b(v.y), f2b(v.z), f2b(v.w));
}

// ---------------------------------------------------------------------------
// MFMA bf16 GEMM: xib = bf16(x @ W_aff^T + b_aff) into xcat right half.
// Reads x (f32) directly and write-throughs xb (bf16) into xcat left half
// during staging — deletes the separate cvt pass (51MB read + 26MB write).
// ---------------------------------------------------------------------------
__global__ __launch_bounds__(256) void mgemm_k(
    const float* __restrict__ x, unsigned short* __restrict__ xcat,
    const float* __restrict__ W, const float* __restrict__ bias, int N) {
  constexpr int LDA = 72;
  __shared__ unsigned short As[128 * LDA];
  __shared__ unsigned short Ws[128 * LDA];

  const int tid = threadIdx.x;
  const int lane = tid & 63;
  const int wave = tid >> 6;
  const int row0 = blockIdx.x * 128;
  const int rowhalf = (wave & 1) * 64;
  const int colhalf = (wave >> 1) * 64;
  const int l15 = lane & 15;
  const int quad = lane >> 4;

  f32x4 acc[4][4] = {};

  for (int kc = 0; kc < 128; kc += 64) {
#pragma unroll
    for (int i = 0; i < 4; i++) {
      int idx = tid + i * 256;
      int r = idx >> 3;
      int k8 = (idx & 7) * 8;
      int row = row0 + r;
      ushort4 u0 = make_ushort4(0, 0, 0, 0), u1 = u0;
      if (row < N) {
        const float* s = x + (size_t)row * 128 + kc + k8;
        u0 = f2b4(*(const float4*)s);
        u1 = f2b4(*(const float4*)(s + 4));
        // write-through xb into xcat left half
        *(ushort4*)&xcat[(size_t)row * 256 + kc + k8] = u0;
        *(ushort4*)&xcat[(size_t)row * 256 + kc + k8 + 4] = u1;
      }
      *(ushort4*)&As[r * LDA + k8] = u0;
      *(ushort4*)&As[r * LDA + k8 + 4] = u1;
    }
#pragma unroll
    for (int i = 0; i < 8; i++) {
      int idx = tid + i * 256;
      int r = idx >> 4;
      int k4 = idx & 15;
      float4 v = *(const float4*)(W + (size_t)r * 128 + kc + k4 * 4);
      *(ushort4*)&Ws[r * LDA + k4 * 4] = f2b4(v);
    }
    __syncthreads();
#pragma unroll
    for (int ks = 0; ks < 2; ks++) {
      const int ko = ks * 32 + quad * 8;
      bf16x8 af[4], wf[4];
#pragma unroll
      for (int ri = 0; ri < 4; ri++)
        af[ri] = *(const bf16x8*)&As[(rowhalf + ri * 16 + l15) * LDA + ko];
#pragma unroll
      for (int ci = 0; ci < 4; ci++)
        wf[ci] = *(const bf16x8*)&Ws[(colhalf + ci * 16 + l15) * LDA + ko];
#pragma unroll
      for (int ri = 0; ri < 4; ri++)
#pragma unroll
        for (int ci = 0; ci < 4; ci++)
          acc[ri][ci] = __builtin_amdgcn_mfma_f32_16x16x32_bf16(
              af[ri], wf[ci], acc[ri][ci], 0, 0, 0);
    }
    __syncthreads();
  }
#pragma unroll
  for (int ci = 0; ci < 4; ci++) {
    const int col = colhalf + ci * 16 + l15;
    const float bv = bias[col];
#pragma unroll
    for (int ri = 0; ri < 4; ri++) {
      const int rbase = row0 + rowhalf + ri * 16 + quad * 4;
#pragma unroll
      for (int r = 0; r < 4; r++) {
        int row = rbase + r;
        if (row >= N) continue;
        xcat[(size_t)row * 256 + 128 + col] = f2b(acc[ri][ci][r] + bv);
      }
    }
  }
}

// ---------------------------------------------------------------------------
// FUSED GRU + backbone, 64-row tiles, 8 waves (512 thr), 2 blocks/CU.
// Writes pre-BN output as bf16 into hout (aliases aggs). setprio(1) around
// MFMA clusters (T5). Stats from f32 regs.
// ---------------------------------------------------------------------------
__global__ __launch_bounds__(512, 4) void grubb_k(
    const unsigned short* __restrict__ aggm,
    const unsigned short* __restrict__ xcat,
    const unsigned short* __restrict__ aggs,
    const unsigned short* __restrict__ Wbig,
    const float* __restrict__ bias_big,
    const unsigned short* __restrict__ Wmb, const float* __restrict__ bm,
    const unsigned short* __restrict__ W1b, const float* __restrict__ b1,
    const unsigned short* __restrict__ W2b, const float* __restrict__ b2,
    const float* __restrict__ epsp, unsigned short* __restrict__ hout,
    float* __restrict__ pstats, int N) {
  constexpr int LDA = 264;  // 256 + 8 pad (ushorts)
  constexpr int LDH = 136;  // 128 + 8 pad
  __shared__ unsigned short As[64 * LDA];    // [aggm | xb]; later Hd alias
  __shared__ unsigned short Acat[64 * LDA];  // [aggs | rnn]; later Hp alias
  __shared__ float sbn[128], qbn[128];
  unsigned short* Hd = As;    // As dead after Hp-write phase
  unsigned short* Hp = Acat;  // Acat dead after merge MFMA

  const int tid = threadIdx.x;
  const int lane = tid & 63;
  const int wave = tid >> 6;  // 0..7
  const int l15 = lane & 15;
  const int quad = lane >> 4;
  const int row0 = blockIdx.x * 64;
  if (tid < 128) {
    sbn[tid] = 0.f;
    qbn[tid] = 0.f;
  }
  const float ep = epsp[0];
  const int f = wave * 16 + l15;  // this lane's feature / output col

  {  // phase 0: stage As (32 ushorts/thread) + Acat left (16 ushorts/thread)
    int r = tid >> 3;  // 0..63
    int q = tid & 7;
    int row = row0 + r;
    int k32 = q * 32;
    uint4 u[4] = {};
    uint4 v[2] = {};
    if (row < N) {
      const unsigned short* s = (k32 < 128)
                                    ? aggm + (size_t)row * 128 + k32
                                    : xcat + (size_t)row * 256 + (k32 - 128);
#pragma unroll
      for (int i = 0; i < 4; i++) u[i] = *(const uint4*)(s + i * 8);
      const unsigned short* s2 = aggs + (size_t)row * 128 + q * 16;
      v[0] = *(const uint4*)s2;
      v[1] = *(const uint4*)(s2 + 8);
    }
#pragma unroll
    for (int i = 0; i < 4; i++) *(uint4*)&As[r * LDA + k32 + i * 8] = u[i];
    *(uint4*)&Acat[r * LDA + q * 16] = v[0];
    *(uint4*)&Acat[r * LDA + q * 16 + 8] = v[1];
  }
  __syncthreads();  // B1

  {  // phase 1: GRU MFMA, 64 rows, zero-skip on gate2/gate3 half-K
    const unsigned short* wp[4];
#pragma unroll
    for (int g = 0; g < 4; g++)
      wp[g] = Wbig +
              (size_t)((wave >> 1) * 128 + (g + 4 * (wave & 1)) * 16 + l15) *
                  256 +
              quad * 8;
    f32x4 acc[4][4] = {};
    __builtin_amdgcn_s_setprio(1);
#pragma unroll
    for (int ks = 0; ks < 8; ks++) {
      const int ko = ks * 32 + quad * 8;
      bf16x8 af[4];
#pragma unroll
      for (int ri = 0; ri < 4; ri++)
        af[ri] = *(const bf16x8*)&As[(ri * 16 + l15) * LDA + ko];
#pragma unroll
      for (int g = 0; g < 4; g++) {
        if (g == 2 && ks >= 4) continue;  // W_ih n-gate: zero for k>=128
        if (g == 3 && ks < 4) continue;   // W_hh n-gate: zero for k<128
        bf16x8 wf = *(const bf16x8*)(wp[g] + ks * 32);
#pragma unroll
        for (int ri = 0; ri < 4; ri++)
          acc[ri][g] = __builtin_amdgcn_mfma_f32_16x16x32_bf16(
              af[ri], wf, acc[ri][g], 0, 0, 0);
      }
    }
    __builtin_amdgcn_s_setprio(0);
    // register GRU: acc[ri][g][r], row rl = ri*16 + quad*4 + r
    const float br = bias_big[f];
    const float bz = bias_big[128 + f];
    const float bi = bias_big[256 + f];
    const float bh = bias_big[384 + f];
#pragma unroll
    for (int ri = 0; ri < 4; ri++) {
#pragma unroll
      for (int r = 0; r < 4; r++) {
        int rl = ri * 16 + quad * 4 + r;
        float rg = 1.f / (1.f + __expf(-(acc[ri][0][r] + br)));
        float zg = 1.f / (1.f + __expf(-(acc[ri][1][r] + bz)));
        float a = acc[ri][2][r] + bi + rg * (acc[ri][3][r] + bh);
        float t = 1.f - 2.f / (__expf(2.f * fabsf(a)) + 1.f);
        float nc = copysignf(t, a);
        float xv = b2f(As[rl * LDA + 128 + f]);  // xb staged in LDS
        Acat[rl * LDA + 128 + f] = f2b((1.f - zg) * nc + zg * xv);
      }
    }
  }
  __syncthreads();  // B2

  f32x4 accm[4] = {};
  {  // phase 2: merge MFMA (K=256 over Acat); wave w -> col f
    const unsigned short* wptr = Wmb + (size_t)f * 256 + quad * 8;
    __builtin_amdgcn_s_setprio(1);
#pragma unroll
    for (int ks = 0; ks < 8; ks++) {
      const int ko = ks * 32 + quad * 8;
      bf16x8 w0 = *(const bf16x8*)(wptr + ks * 32);
#pragma unroll
      for (int ri = 0; ri < 4; ri++) {
        bf16x8 af = *(const bf16x8*)&Acat[(ri * 16 + l15) * LDA + ko];
        accm[ri] = __builtin_amdgcn_mfma_f32_16x16x32_bf16(af, w0, accm[ri],
                                                           0, 0, 0);
      }
    }
    __builtin_amdgcn_s_setprio(0);
  }
  __syncthreads();  // B3: all Acat readers done before Hp overwrite
  {  // merge epilogue: + bm + eps*xb -> Hp (aliases Acat)
    float bv = bm[f];
#pragma unroll
    for (int ri = 0; ri < 4; ri++) {
#pragma unroll
      for (int r = 0; r < 4; r++) {
        int rl = ri * 16 + quad * 4 + r;
        float v = accm[ri][r] + bv + ep * b2f(As[rl * LDA + 128 + f]);
        Hp[rl * LDH + f] = f2b(v);
      }
    }
  }
  __syncthreads();  // B4

  f32x4 acc3[4] = {};
#pragma unroll
  for (int hh = 0; hh < 2; hh++) {
    // W1 half hh: Hd = relu(Hp @ W1[hh*128..+128]^T + b1); wave w -> col f
    f32x4 acc2[4] = {};
    {
      const unsigned short* wptr =
          W1b + (size_t)(hh * 128 + f) * 128 + quad * 8;
      __builtin_amdgcn_s_setprio(1);
#pragma unroll
      for (int ks = 0; ks < 4; ks++) {
        const int ko = ks * 32 + quad * 8;
        bf16x8 w0 = *(const bf16x8*)(wptr + ks * 32);
#pragma unroll
        for (int ri = 0; ri < 4; ri++) {
          bf16x8 af = *(const bf16x8*)&Hp[(ri * 16 + l15) * LDH + ko];
          acc2[ri] = __builtin_amdgcn_mfma_f32_16x16x32_bf16(af, w0, acc2[ri],
                                                             0, 0, 0);
        }
      }
      __builtin_amdgcn_s_setprio(0);
    }
    __syncthreads();  // prior Hd readers (W2 of hh-1) done before overwrite
    {
      float bv = b1[hh * 128 + f];
#pragma unroll
      for (int ri = 0; ri < 4; ri++) {
#pragma unroll
        for (int r = 0; r < 4; r++) {
          int rl = ri * 16 + quad * 4 + r;
          Hd[rl * LDH + f] = f2b(fmaxf(acc2[ri][r] + bv, 0.f));
        }
      }
    }
    __syncthreads();
    // W2 half hh: acc3 += Hd @ W2[:, hh*128..+128]^T
    {
      const unsigned short* wptr =
          W2b + (size_t)f * 256 + hh * 128 + quad * 8;
      __builtin_amdgcn_s_setprio(1);
#pragma unroll
      for (int ks = 0; ks < 4; ks++) {
        const int ko = ks * 32 + quad * 8;
        bf16x8 w0 = *(const bf16x8*)(wptr + ks * 32);
#pragma unroll
        for (int ri = 0; ri < 4; ri++) {
          bf16x8 af = *(const bf16x8*)&Hd[(ri * 16 + l15) * LDH + ko];
          acc3[ri] = __builtin_amdgcn_mfma_f32_16x16x32_bf16(af, w0, acc3[ri],
                                                             0, 0, 0);
        }
      }
      __builtin_amdgcn_s_setprio(0);
    }
  }
  // epilogue: relu + hout (bf16) + BN partials (f32, from regs)
  {
    float bv = b2[f];
    float s = 0.f, q = 0.f;
#pragma unroll
    for (int ri = 0; ri < 4; ri++) {
#pragma unroll
      for (int r = 0; r < 4; r++) {
        int rl = ri * 16 + quad * 4 + r;
        int row = row0 + rl;
        if (row >= N) continue;
        float v = fmaxf(acc3[ri][r] + bv, 0.f);
        hout[(size_t)row * 128 + f] = f2b(v);
        s += v;
        q += v * v;
      }
    }
    atomicAdd(&sbn[f], s);
    atomicAdd(&qbn[f], q);
  }
  __syncthreads();
  if (tid < 128) {
    float* p = pstats + (size_t)blockIdx.x * 256;
    p[tid] = sbn[tid];
    p[128 + tid] = qbn[tid];
  }
}

// ---------------------------------------------------------------------------
// bnred: reduce per-block partials -> stats (few, well-spread atomics)
// ---------------------------------------------------------------------------
__global__ __launch_bounds__(256) void bnred_k(const float* __restrict__ pstats,
                                               float* __restrict__ stats,
                                               int nb) {
  int t = threadIdx.x;
  float s = 0.f;
  for (int b = blockIdx.x; b < nb; b += gridDim.x)
    s += pstats[(size_t)b * 256 + t];
  atomicAdd(&stats[t], s);
}

// ---------------------------------------------------------------------------
// prep: permuted Wbig, Wmb/W1b/W2b bf16 copies, bias_big, zero stats + deg.
// ---------------------------------------------------------------------------
__global__ __launch_bounds__(256) void prep_k(
    const float* __restrict__ W_ih, const float* __restrict__ b_ih,
    const float* __restrict__ W_hh, const float* __restrict__ b_hh,
    const float* __restrict__ Wm, const float* __restrict__ W1,
    const float* __restrict__ W2, unsigned short* __restrict__ Wbig,
    unsigned short* __restrict__ Wmb, unsigned short* __restrict__ W1b,
    unsigned short* __restrict__ W2b, float* __restrict__ bias_big,
    float* __restrict__ stats, int* __restrict__ deg, int N) {
  int idx = blockIdx.x * 256 + threadIdx.x;
  if (idx < N) deg[idx] = 0;
  if (idx < 32768) {  // permuted Wbig: col c -> (gate g, feature f)
    int mp = idx >> 6;
    int k4 = (idx & 63) * 4;
    int w = mp >> 7, ci = (mp >> 4) & 7, l15 = mp & 15;
    int g = ci & 3, fi = ci >> 2;
    int f = w * 32 + fi * 16 + l15;
    const float* src = nullptr;
    int koff = 0;
    if (g <= 1) {
      int m = g * 128 + f;
      if (k4 < 128) { src = W_ih + (size_t)m * 128; koff = k4; }
      else          { src = W_hh + (size_t)m * 128; koff = k4 - 128; }
    } else if (g == 2) {
      if (k4 < 128) { src = W_ih + (size_t)(256 + f) * 128; koff = k4; }
    } else {
      if (k4 >= 128) { src = W_hh + (size_t)(256 + f) * 128; koff = k4 - 128; }
    }
    ushort4 o = make_ushort4(0, 0, 0, 0);
    if (src) o = f2b4(*(const float4*)(src + koff));
    *(ushort4*)&Wbig[(size_t)mp * 256 + k4] = o;
  }
  if (idx < 8192) {
    int m = idx >> 6;
    int k4 = (idx & 63) * 4;
    *(ushort4*)&Wmb[(size_t)m * 256 + k4] =
        f2b4(*(const float4*)(Wm + (size_t)m * 256 + k4));
    *(ushort4*)&W2b[(size_t)m * 256 + k4] =
        f2b4(*(const float4*)(W2 + (size_t)m * 256 + k4));
    int m2 = idx >> 5;
    int k42 = (idx & 31) * 4;
    *(ushort4*)&W1b[(size_t)m2 * 128 + k42] =
        f2b4(*(const float4*)(W1 + (size_t)m2 * 128 + k42));
  }
  if (blockIdx.x == 0) {
    int t = threadIdx.x;
    stats[t] = 0.f;
#pragma unroll
    for (int h = 0; h < 2; h++) {
      int mm = t + h * 256;
      float b;
      if (mm < 256) b = b_ih[mm] + b_hh[mm];
      else if (mm < 384) b = b_ih[mm];
      else b = b_hh[mm - 128];
      bias_big[mm] = b;
    }
  }
}

// ---------------------------------------------------------------------------
// hist: per-node in-degree histogram
// ---------------------------------------------------------------------------
__global__ __launch_bounds__(256) void hist_k(const int* __restrict__ edges,
                                              int* __restrict__ deg, int E) {
  int e = blockIdx.x * 256 + threadIdx.x;
  if (e < E) atomicAdd(&deg[edges[(size_t)E + e]], 1);
}

// ---------------------------------------------------------------------------
// CSR scan
// ---------------------------------------------------------------------------
__global__ __launch_bounds__(256) void scan1_k(const int* __restrict__ deg,
                                               int* __restrict__ off,
                                               int* __restrict__ bsums, int N) {
  __shared__ int s[256];
  int t = threadIdx.x;
  int i = blockIdx.x * 256 + t;
  int v = (i < N) ? deg[i] : 0;
  s[t] = v;
  __syncthreads();
#pragma unroll
  for (int d = 1; d < 256; d <<= 1) {
    int u = (t >= d) ? s[t - d] : 0;
    __syncthreads();
    s[t] += u;
    __syncthreads();
  }
  if (i < N) off[i] = s[t] - v;
  if (t == 255) bsums[blockIdx.x] = s[255];
}

__global__ __launch_bounds__(512) void scan2_k(int* __restrict__ bsums,
                                               int nb) {
  __shared__ int s[512];
  int t = threadIdx.x;
  int v = (t < nb) ? bsums[t] : 0;
  s[t] = v;
  __syncthreads();
#pragma unroll
  for (int d = 1; d < 512; d <<= 1) {
    int u = (t >= d) ? s[t - d] : 0;
    __syncthreads();
    s[t] += u;
    __syncthreads();
  }
  if (t < nb) bsums[t] = s[t] - v;
}

// scan3: finalize off[] and also emit per-bin (512 nodes) offsets + cursors.
__global__ __launch_bounds__(256) void scan3_k(int* __restrict__ off,
                                               const int* __restrict__ bsums,
                                               int* __restrict__ binoff,
                                               int* __restrict__ bincur,
                                               int N, int E, int NB) {
  int i = blockIdx.x * 256 + threadIdx.x;
  if (i < N) {
    int o = off[i] + bsums[blockIdx.x];
    off[i] = o;
    if ((i & 511) == 0) {
      binoff[i >> 9] = o;
      bincur[i >> 9] = o;
    }
  }
  if (i == 0) {
    off[N] = E;
    binoff[NB] = E;
  }
}

// ---------------------------------------------------------------------------
// edgepart: bin edges by dst>>9 into part[] (packed (src<<9)|(dst&511)).
// ---------------------------------------------------------------------------
__global__ __launch_bounds__(256) void edgepart_k(const int* __restrict__ edges,
                                                  int* __restrict__ bincur,
                                                  int* __restrict__ part,
                                                  int E, int NB) {
  __shared__ int cnt[256];
  const int tid = threadIdx.x;
  if (tid < NB) cnt[tid] = 0;
  __syncthreads();
  int sv[16], dv[16];
  const int e0 = blockIdx.x * 4096;
#pragma unroll
  for (int i = 0; i < 16; i++) {
    int e = e0 + i * 256 + tid;
    int s = 0, d = -1;
    if (e < E) {
      s = edges[e];
      d = edges[(size_t)E + e];
    }
    sv[i] = s;
    dv[i] = d;
    if (d >= 0) atomicAdd(&cnt[d >> 9], 1);
  }
  __syncthreads();
  if (tid < NB) {
    int c = cnt[tid];
    int base = c ? atomicAdd(&bincur[tid], c) : 0;
    cnt[tid] = base;  // becomes running cursor
  }
  __syncthreads();
#pragma unroll
  for (int i = 0; i < 16; i++) {
    int d = dv[i];
    if (d < 0) continue;
    int p = atomicAdd(&cnt[d >> 9], 1);
    part[p] = (sv[i] << 9) | (d & 511);
  }
}

// ---------------------------------------------------------------------------
// fill2: one block per bin; node cursors in LDS; writes confined to the
// bin's contiguous bucket window.
// ---------------------------------------------------------------------------
__global__ __launch_bounds__(1024) void fill2_k(const int* __restrict__ off,
                                                const int* __restrict__ binoff,
                                                const int* __restrict__ part,
                                                int* __restrict__ bucket,
                                                int N) {
  __shared__ int scur[512];
  const int b = blockIdx.x;
  const int n0 = b << 9;
  const int tid = threadIdx.x;
  if (tid < 512) {
    int node = n0 + tid;
    scur[tid] = (node < N) ? off[node] : 0;
  }
  __syncthreads();
  const int j0 = binoff[b];
  const int j1 = binoff[b + 1];
  for (int j = j0 + tid; j < j1; j += 1024) {
    int p = part[j];
    int pos = atomicAdd(&scur[p & 511], 1);
    bucket[pos] = p >> 9;
  }
}

// ---------------------------------------------------------------------------
// gather-reduce: one wave/node, QUARTER-wave edge split — 4 edges in flight,
// 16 lanes/edge, 8 features/lane via 16B uint4 loads. Two-level
// shfl_xor(16/32) combine. Writes aggs + aggm. (Measured optimum r16.)
// ---------------------------------------------------------------------------
__global__ __launch_bounds__(256) void gather_k(
    const int* __restrict__ off, const int* __restrict__ bucket,
    const unsigned short* __restrict__ xcat, unsigned short* __restrict__ aggm,
    unsigned short* __restrict__ aggs, int N) {
  int node = blockIdx.x * 4 + (threadIdx.x >> 6);
  if (node >= N) return;
  const int lane = threadIdx.x & 63;
  const int qw = lane >> 4;        // quarter index 0..3
  const int f8 = (lane & 15) * 8;  // 8 features per lane
  const int j0 = off[node], jend = off[node + 1];
  float s[8], m[8];
#pragma unroll
  for (int i = 0; i < 8; i++) {
    s[i] = 0.f;
    m[i] = -INFINITY;
  }
  int jj = j0 + qw;
  int p0 = (jj < jend) ? bucket[jj] : 0;
  int p1 = (jj + 4 < jend) ? bucket[jj + 4] : 0;
  for (; jj < jend; jj += 4) {
    int src = p0;
    p0 = p1;
    p1 = (jj + 8 < jend) ? bucket[jj + 8] : 0;
    uint4 a = *(const uint4*)(xcat + (size_t)src * 256 + f8);
    uint4 b = *(const uint4*)(xcat + (size_t)src * 256 + 128 + f8);
    const unsigned short* ap = (const unsigned short*)&a;
    const unsigned short* bp = (const unsigned short*)&b;
#pragma unroll
    for (int i = 0; i < 8; i++) {
      s[i] += b2f(ap[i]);
      m[i] = fmaxf(m[i], b2f(bp[i]));
    }
  }
  // combine the four quarter-waves
#pragma unroll
  for (int i = 0; i < 8; i++) {
    s[i] += __shfl_xor(s[i], 16);
    s[i] += __shfl_xor(s[i], 32);
    m[i] = fmaxf(m[i], __shfl_xor(m[i], 16));
    m[i] = fmaxf(m[i], __shfl_xor(m[i], 32));
  }
  if (qw == 0) {
    bool nz = jend > j0;
    unsigned short mv[8], sv[8];
#pragma unroll
    for (int i = 0; i < 8; i++) {
      mv[i] = nz ? f2b(m[i]) : (unsigned short)0;
      sv[i] = f2b(s[i]);
    }
    *(uint4*)&aggm[(size_t)node * 128 + f8] = *(const uint4*)mv;
    *(uint4*)&aggs[(size_t)node * 128 + f8] = *(const uint4*)sv;
  }
}

// ---------------------------------------------------------------------------
// BatchNorm apply: read pre-BN bf16 hout, write final f32 out.
// ---------------------------------------------------------------------------
__global__ __launch_bounds__(256) void bn_apply_k(
    float* __restrict__ out, const unsigned short* __restrict__ hout,
    const float* __restrict__ stats, const float* __restrict__ gamma,
    const float* __restrict__ beta, float invn, int nd4) {
  int g = blockIdx.x * 256 + threadIdx.x;
  if (g >= nd4) return;
  int d = (g & 31) * 4;
  ushort4 hv = ((const ushort4*)hout)[g];
  float o[4] = {b2f(hv.x), b2f(hv.y), b2f(hv.z), b2f(hv.w)};
#pragma unroll
  for (int i = 0; i < 4; i++) {
    float mean = stats[d + i] * invn;
    float var = fmaxf(stats[128 + d + i] * invn - mean * mean, 0.f);
    float sc = gamma[d + i] * rsqrtf(var + 1e-5f);
    o[i] = (o[i] - mean) * sc + beta[d + i];
  }
  ((float4*)out)[g] = make_float4(o[0], o[1], o[2], o[3]);
}

// ---------------------------------------------------------------------------
extern "C" void kernel_launch(void* const* d_in, const int* in_sizes, int n_in,
                              void* d_out, int out_size, void* d_ws,
                              size_t ws_size, hipStream_t stream) {
  (void)n_in;
  (void)out_size;
  (void)ws_size;
  const float* x = (const float*)d_in[0];
  const int* edges = (const int*)d_in[1];
  const float* W_aff = (const float*)d_in[2];
  const float* b_aff = (const float*)d_in[3];
  const float* W_ih = (const float*)d_in[4];
  const float* b_ih = (const float*)d_in[5];
  const float* W_hh = (const float*)d_in[6];
  const float* b_hh = (const float*)d_in[7];
  const float* W_merge = (const float*)d_in[8];
  const float* b_merge = (const float*)d_in[9];
  const float* epsp = (const float*)d_in[10];
  const float* W1 = (const float*)d_in[11];
  const float* b1 = (const float*)d_in[12];
  const float* W2 = (const float*)d_in[13];
  const float* b2 = (const float*)d_in[14];
  const float* gamma = (const float*)d_in[15];
  const float* beta = (const float*)d_in[16];

  const int N = in_sizes[0] / 128;
  const int E = in_sizes[1] / 2;
  const size_t nd = (size_t)N * 128;
  const int NB = (N + 511) >> 9;   // 512-node bins
  const int gblk = (N + 63) / 64;  // grubb grid (64-row tiles)

  // ---- workspace ----
  char* base = (char*)d_ws;
  unsigned short* xcat = (unsigned short*)base;               // [xb|xib] Nx256
  unsigned short* aggs = (unsigned short*)(base + (size_t)N * 512);  // Nx128 sum
  unsigned short* aggm = (unsigned short*)(base + (size_t)N * 1024); // Nx128 max
  unsigned short* Wbig = (unsigned short*)(base + (size_t)N * 1280);
  unsigned short* Wmb = Wbig + 512 * 256;
  unsigned short* W1b = Wmb + 128 * 256;
  unsigned short* W2b = W1b + 256 * 128;
  float* bias_big = (float*)(W2b + 128 * 256);
  float* stats = bias_big + 512;
  int* deg = (int*)(stats + 512);
  int* off = deg + N;
  int* binoff = off + N + 1;
  int* bincur = binoff + NB + 1;
  int* bucket = bincur + NB;
  int* bsums = bucket + E;
  float* pstats = (float*)(bsums + ((N + 255) / 256));  // gblk x 256 partials
  float* out = (float*)d_out;
  // hout (pre-BN bf16) aliases aggs: block b's hout rows are exactly the
  // aggs rows only block b reads (phase 0), disjoint across blocks.
  unsigned short* hout = aggs;
  // part[] (E ints) lives in d_out: dead before bn_apply writes out.
  int* part = (int*)d_out;

  const int ny = (N + 127) / 128;
  const int nblk = (N + 255) / 256;
  const int eblk = (E + 255) / 256;
  const int pgrid = nblk > 128 ? nblk : 128;
  dim3 blk(256);

  prep_k<<<pgrid, blk, 0, stream>>>(W_ih, b_ih, W_hh, b_hh, W_merge, W1, W2,
                                    Wbig, Wmb, W1b, W2b, bias_big, stats, deg,
                                    N);
  hist_k<<<eblk, blk, 0, stream>>>(edges, deg, E);
  scan1_k<<<nblk, blk, 0, stream>>>(deg, off, bsums, N);
  scan2_k<<<1, 512, 0, stream>>>(bsums, nblk);
  scan3_k<<<nblk, blk, 0, stream>>>(off, bsums, binoff, bincur, N, E, NB);
  edgepart_k<<<(E + 4095) / 4096, blk, 0, stream>>>(edges, bincur, part, E, NB);
  fill2_k<<<NB, dim3(1024), 0, stream>>>(off, binoff, part, bucket, N);

  // xb (write-through) + xib = bf16(x @ W_aff^T + b_aff) into xcat
  mgemm_k<<<ny, blk, 0, stream>>>(x, xcat, W_aff, b_aff, N);
  gather_k<<<(N + 3) / 4, blk, 0, stream>>>(off, bucket, xcat, aggm, aggs, N);
  grubb_k<<<gblk, dim3(512), 0, stream>>>(aggm, xcat, aggs, Wbig, bias_big,
                                          Wmb, b_merge, W1b, b1, W2b, b2,
                                          epsp, hout, pstats, N);
  bnred_k<<<64, blk, 0, stream>>>(pstats, stats, gblk);
  bn_apply_k<<<(int)((nd / 4 + 255) / 256), blk, 0, stream>>>(
      out, hout, stats, gamma, beta, 1.f / (float)N, (int)(nd / 4));
}